// Round 1
// baseline (8928.185 us; speedup 1.0000x reference)
//
#include <hip/hip_runtime.h>

namespace {
constexpr int kB = 4, kT = 4096, kD = 1024, kE = 8, kH = 4096;
constexpr int kN = kB * kT;   // 16384 tokens
constexpr int kCap = 4096;    // N*TOP_K/E * CAPACITY_FACTOR
}

// ---------------- zero output ----------------
__global__ __launch_bounds__(256) void moe_zero_out(float4* __restrict__ p, int n4)
{
    int i = blockIdx.x * 256 + threadIdx.x;
    if (i < n4) p[i] = make_float4(0.f, 0.f, 0.f, 0.f);
}

// ---------------- router: one wave per token ----------------
__global__ __launch_bounds__(256) void moe_router(
    const float* __restrict__ x, const float* __restrict__ noise_raw,
    const float* __restrict__ Wr, const float* __restrict__ br,
    const float* __restrict__ Wn, const float* __restrict__ bn,
    int2* __restrict__ topIdx, float2* __restrict__ topProb)
{
    const int wave = threadIdx.x >> 6;
    const int lane = threadIdx.x & 63;
    const int n = blockIdx.x * 4 + wave;
    const float* xr = x + (size_t)n * kD;

    float accr[kE], accn[kE];
    #pragma unroll
    for (int e = 0; e < kE; ++e) { accr[e] = 0.f; accn[e] = 0.f; }

    #pragma unroll
    for (int c = 0; c < 4; ++c) {
        const int d0 = c * 256 + lane * 4;
        const float4 xv = *(const float4*)(xr + d0);
        const float xs[4] = {xv.x, xv.y, xv.z, xv.w};
        #pragma unroll
        for (int j = 0; j < 4; ++j) {
            const float4* wr4 = (const float4*)(Wr + (size_t)(d0 + j) * kE);
            const float4* wn4 = (const float4*)(Wn + (size_t)(d0 + j) * kE);
            const float4 r0 = wr4[0], r1 = wr4[1];
            const float4 m0 = wn4[0], m1 = wn4[1];
            const float xj = xs[j];
            accr[0] += xj * r0.x; accr[1] += xj * r0.y; accr[2] += xj * r0.z; accr[3] += xj * r0.w;
            accr[4] += xj * r1.x; accr[5] += xj * r1.y; accr[6] += xj * r1.z; accr[7] += xj * r1.w;
            accn[0] += xj * m0.x; accn[1] += xj * m0.y; accn[2] += xj * m0.z; accn[3] += xj * m0.w;
            accn[4] += xj * m1.x; accn[5] += xj * m1.y; accn[6] += xj * m1.z; accn[7] += xj * m1.w;
        }
    }
    #pragma unroll
    for (int e = 0; e < kE; ++e) {
        #pragma unroll
        for (int off = 32; off >= 1; off >>= 1) {
            accr[e] += __shfl_xor(accr[e], off, 64);
            accn[e] += __shfl_xor(accn[e], off, 64);
        }
    }
    if (lane == 0) {
        float noisy[kE];
        #pragma unroll
        for (int e = 0; e < kE; ++e) {
            const float lg = accr[e] + br[e];
            const float nl = accn[e] + bn[e];
            // stable softplus == jnp.logaddexp(x, 0)
            const float sp = fmaxf(nl, 0.f) + log1pf(expf(-fabsf(nl)));
            noisy[e] = lg + noise_raw[(size_t)n * kE + e] * sp;
        }
        int i0 = 0;
        #pragma unroll
        for (int e = 1; e < kE; ++e) if (noisy[e] > noisy[i0]) i0 = e;   // first max (tie -> low idx)
        int i1 = (i0 == 0) ? 1 : 0;
        #pragma unroll
        for (int e = 0; e < kE; ++e) if (e != i0 && noisy[e] > noisy[i1]) i1 = e;
        const float ex = expf(noisy[i1] - noisy[i0]);   // v1 <= v0 -> stable
        topIdx[n] = make_int2(i0, i1);
        topProb[n] = make_float2(1.f / (1.f + ex), ex / (1.f + ex));
    }
}

// ---------------- dispatch: stable compaction in flat token order ----------------
__global__ void moe_dispatch(
    const int2* __restrict__ topIdx, const float2* __restrict__ topProb,
    int* __restrict__ tokList, float* __restrict__ gateList, int* __restrict__ cnt)
{
    const int e = blockIdx.x;       // one wave per expert
    const int lane = threadIdx.x;   // block = 64
    const unsigned long long below = (lane == 0) ? 0ull : ((~0ull) >> (64 - lane));
    int base = 0;
    for (int it = 0; it < kN / 64; ++it) {
        const int n = it * 64 + lane;
        const int2 ti = topIdx[n];
        const float2 tp = topProb[n];
        const bool sel = (ti.x == e) || (ti.y == e);
        const float g = (ti.x == e) ? tp.x : tp.y;
        const unsigned long long m = __ballot(sel);
        if (sel) {
            const int slot = base + __popcll(m & below);
            if (slot < kCap) { tokList[e * kCap + slot] = n; gateList[e * kCap + slot] = g; }
        }
        base += __popcll(m);
    }
    if (lane == 0) cnt[e] = base < kCap ? base : kCap;
}

// ---------------- FFN pass 1: H = relu(Xg @ W1[e] + b1[e]),  M<=4096, N=4096, K=1024 ----------------
// 128x128 tile, BK=16, 256 threads, 8x8 micro-tile (split 4+4 rows/cols for LDS bank behavior)
__global__ __launch_bounds__(256) void moe_ffn1(
    const float* __restrict__ x, const float* __restrict__ W1,
    const float* __restrict__ bias1,
    const int* __restrict__ tokList, const int* __restrict__ cnt,
    float* __restrict__ Hbuf, size_t hbuf_stride, int e_base)
{
    const int e = e_base + blockIdx.z;
    const int count = cnt[e];
    const int m0 = blockIdx.y * 128;
    if (m0 >= count) return;
    const int n0 = blockIdx.x * 128;

    const float* __restrict__ W = W1 + (size_t)e * kD * kH + n0;
    const float* __restrict__ bias = bias1 + (size_t)e * kH + n0;
    const int* __restrict__ tok = tokList + e * kCap;
    float* __restrict__ Hout = Hbuf + hbuf_stride * blockIdx.z;

    __shared__ float As[16][128];   // k-major (transposed)
    __shared__ float Bs[16][128];

    const int tid = (int)threadIdx.x;
    const int arow0 = tid >> 2;        // 0..63
    const int arow1 = arow0 + 64;
    const int ac4 = (tid & 3) * 4;     // k-offset 0/4/8/12
    const bool av0 = (m0 + arow0) < count;
    const bool av1 = (m0 + arow1) < count;
    const float* ap0 = av0 ? x + (size_t)tok[m0 + arow0] * kD + ac4 : nullptr;
    const float* ap1 = av1 ? x + (size_t)tok[m0 + arow1] * kD + ac4 : nullptr;

    const int brow = tid >> 5;         // 0..7
    const int bc = (tid & 31) * 4;
    const float* bp = W + (size_t)brow * kH + bc;

    const int tx = tid & 15, ty = tid >> 4;

    float acc[8][8];
    #pragma unroll
    for (int i = 0; i < 8; ++i)
        #pragma unroll
        for (int j = 0; j < 8; ++j) acc[i][j] = 0.f;

    const float4 z4 = make_float4(0.f, 0.f, 0.f, 0.f);
    for (int k0 = 0; k0 < kD; k0 += 16) {
        const float4 a0 = av0 ? *(const float4*)(ap0 + k0) : z4;
        const float4 a1 = av1 ? *(const float4*)(ap1 + k0) : z4;
        const float4 bb0 = *(const float4*)(bp + (size_t)k0 * kH);
        const float4 bb1 = *(const float4*)(bp + (size_t)(k0 + 8) * kH);
        __syncthreads();
        As[ac4 + 0][arow0] = a0.x; As[ac4 + 1][arow0] = a0.y;
        As[ac4 + 2][arow0] = a0.z; As[ac4 + 3][arow0] = a0.w;
        As[ac4 + 0][arow1] = a1.x; As[ac4 + 1][arow1] = a1.y;
        As[ac4 + 2][arow1] = a1.z; As[ac4 + 3][arow1] = a1.w;
        *(float4*)&Bs[brow][bc] = bb0;
        *(float4*)&Bs[brow + 8][bc] = bb1;
        __syncthreads();
        #pragma unroll
        for (int kk = 0; kk < 16; ++kk) {
            const float4 aL = *(const float4*)&As[kk][ty * 4];
            const float4 aH = *(const float4*)&As[kk][ty * 4 + 64];
            const float4 bL = *(const float4*)&Bs[kk][tx * 4];
            const float4 bH = *(const float4*)&Bs[kk][tx * 4 + 64];
            const float avv[8] = {aL.x, aL.y, aL.z, aL.w, aH.x, aH.y, aH.z, aH.w};
            const float bvv[8] = {bL.x, bL.y, bL.z, bL.w, bH.x, bH.y, bH.z, bH.w};
            #pragma unroll
            for (int i = 0; i < 8; ++i)
                #pragma unroll
                for (int j = 0; j < 8; ++j)
                    acc[i][j] += avv[i] * bvv[j];
        }
    }

    #pragma unroll
    for (int i = 0; i < 8; ++i) {
        const int rloc = (i < 4) ? (ty * 4 + i) : (64 + ty * 4 + (i - 4));
        const int r = m0 + rloc;
        if (r >= count) continue;
        float* orow = Hout + (size_t)r * kH + n0;
        float4 v;
        v.x = fmaxf(acc[i][0] + bias[tx * 4 + 0], 0.f);
        v.y = fmaxf(acc[i][1] + bias[tx * 4 + 1], 0.f);
        v.z = fmaxf(acc[i][2] + bias[tx * 4 + 2], 0.f);
        v.w = fmaxf(acc[i][3] + bias[tx * 4 + 3], 0.f);
        *(float4*)(orow + tx * 4) = v;
        v.x = fmaxf(acc[i][4] + bias[64 + tx * 4 + 0], 0.f);
        v.y = fmaxf(acc[i][5] + bias[64 + tx * 4 + 1], 0.f);
        v.z = fmaxf(acc[i][6] + bias[64 + tx * 4 + 2], 0.f);
        v.w = fmaxf(acc[i][7] + bias[64 + tx * 4 + 3], 0.f);
        *(float4*)(orow + 64 + tx * 4) = v;
    }
}

// ---------------- FFN pass 2 + gated combine: out[tok] += g * (H @ W2[e] + b2[e]) ----------------
// 64x128 tile, BK=16, 256 threads, 4x8 micro-tile. ATOMIC=0 only safe when experts run sequentially.
template <int ATOMIC>
__global__ __launch_bounds__(256) void moe_ffn2(
    const float* __restrict__ Hbuf, size_t hbuf_stride,
    const float* __restrict__ W2, const float* __restrict__ bias2,
    const int* __restrict__ tokList, const float* __restrict__ gateList,
    const int* __restrict__ cnt, float* __restrict__ out, int e_base)
{
    const int e = e_base + blockIdx.z;
    const int count = cnt[e];
    const int m0 = blockIdx.y * 64;
    if (m0 >= count) return;
    const int n0 = blockIdx.x * 128;

    const float* __restrict__ Hin = Hbuf + hbuf_stride * blockIdx.z;
    const float* __restrict__ W = W2 + (size_t)e * kH * kD + n0;
    const float* __restrict__ bias = bias2 + (size_t)e * kD + n0;
    const int* __restrict__ tok = tokList + e * kCap;
    const float* __restrict__ gate = gateList + e * kCap;

    __shared__ float As[16][64];
    __shared__ float Bs[16][128];

    const int tid = (int)threadIdx.x;
    const int arow = tid >> 2;         // 0..63
    const int ac4 = (tid & 3) * 4;
    const bool av = (m0 + arow) < count;
    const float* ap = av ? Hin + (size_t)(m0 + arow) * kH + ac4 : nullptr;

    const int brow = tid >> 5;
    const int bc = (tid & 31) * 4;
    const float* bp = W + (size_t)brow * kD + bc;

    const int tx = tid & 15, ty = tid >> 4;

    float acc[4][8];
    #pragma unroll
    for (int i = 0; i < 4; ++i)
        #pragma unroll
        for (int j = 0; j < 8; ++j) acc[i][j] = 0.f;

    const float4 z4 = make_float4(0.f, 0.f, 0.f, 0.f);
    for (int k0 = 0; k0 < kH; k0 += 16) {
        const float4 a0 = av ? *(const float4*)(ap + k0) : z4;
        const float4 bb0 = *(const float4*)(bp + (size_t)k0 * kD);
        const float4 bb1 = *(const float4*)(bp + (size_t)(k0 + 8) * kD);
        __syncthreads();
        As[ac4 + 0][arow] = a0.x; As[ac4 + 1][arow] = a0.y;
        As[ac4 + 2][arow] = a0.z; As[ac4 + 3][arow] = a0.w;
        *(float4*)&Bs[brow][bc] = bb0;
        *(float4*)&Bs[brow + 8][bc] = bb1;
        __syncthreads();
        #pragma unroll
        for (int kk = 0; kk < 16; ++kk) {
            const float4 aL = *(const float4*)&As[kk][ty * 4];
            const float4 bL = *(const float4*)&Bs[kk][tx * 4];
            const float4 bH = *(const float4*)&Bs[kk][tx * 4 + 64];
            const float avv[4] = {aL.x, aL.y, aL.z, aL.w};
            const float bvv[8] = {bL.x, bL.y, bL.z, bL.w, bH.x, bH.y, bH.z, bH.w};
            #pragma unroll
            for (int i = 0; i < 4; ++i)
                #pragma unroll
                for (int j = 0; j < 8; ++j)
                    acc[i][j] += avv[i] * bvv[j];
        }
    }

    #pragma unroll
    for (int i = 0; i < 4; ++i) {
        const int r = m0 + ty * 4 + i;
        if (r >= count) continue;
        const int tokn = tok[r];
        const float g = gate[r];
        float* orow = out + (size_t)tokn * kD + n0;
        #pragma unroll
        for (int j = 0; j < 4; ++j) {
            const float v = (acc[i][j] + bias[tx * 4 + j]) * g;
            if (ATOMIC) atomicAdd(orow + tx * 4 + j, v);
            else        orow[tx * 4 + j] += v;
        }
        #pragma unroll
        for (int j = 0; j < 4; ++j) {
            const float v = (acc[i][4 + j] + bias[64 + tx * 4 + j]) * g;
            if (ATOMIC) atomicAdd(orow + 64 + tx * 4 + j, v);
            else        orow[64 + tx * 4 + j] += v;
        }
    }
}

// ---------------- launch ----------------
extern "C" void kernel_launch(void* const* d_in, const int* in_sizes, int n_in,
                              void* d_out, int out_size, void* d_ws, size_t ws_size,
                              hipStream_t stream)
{
    const float* x         = (const float*)d_in[0];
    const float* noise_raw = (const float*)d_in[1];
    const float* Wr        = (const float*)d_in[2];
    const float* br        = (const float*)d_in[3];
    const float* Wn        = (const float*)d_in[4];
    const float* bn        = (const float*)d_in[5];
    const float* W1        = (const float*)d_in[6];
    const float* b1        = (const float*)d_in[7];
    const float* W2        = (const float*)d_in[8];
    const float* b2        = (const float*)d_in[9];
    float* out = (float*)d_out;

    char* ws = (char*)d_ws;
    size_t off = 0;
    auto alloc = [&](size_t bytes) -> void* {
        void* p = ws + off;
        off = (off + bytes + 255) & ~(size_t)255;
        return p;
    };
    int2*   topIdx   = (int2*)  alloc((size_t)kN * sizeof(int2));
    float2* topProb  = (float2*)alloc((size_t)kN * sizeof(float2));
    int*    tokList  = (int*)   alloc((size_t)kE * kCap * sizeof(int));
    float*  gateList = (float*) alloc((size_t)kE * kCap * sizeof(float));
    int*    cnt      = (int*)   alloc((size_t)kE * sizeof(int));
    float*  Hbuf     = (float*) (ws + off);
    const size_t hbuf_batched_bytes = (size_t)kE * kCap * kH * sizeof(float);
    const bool batched = (ws_size >= off + hbuf_batched_bytes);

    moe_zero_out<<<(kN * kD / 4 + 255) / 256, 256, 0, stream>>>((float4*)out, kN * kD / 4);
    moe_router<<<kN / 4, 256, 0, stream>>>(x, noise_raw, Wr, br, Wn, bn, topIdx, topProb);
    moe_dispatch<<<kE, 64, 0, stream>>>(topIdx, topProb, tokList, gateList, cnt);

    if (batched) {
        const size_t hstride = (size_t)kCap * kH;
        moe_ffn1<<<dim3(kH / 128, kCap / 128, kE), 256, 0, stream>>>(
            x, W1, b1, tokList, cnt, Hbuf, hstride, 0);
        moe_ffn2<1><<<dim3(kD / 128, kCap / 64, kE), 256, 0, stream>>>(
            Hbuf, hstride, W2, b2, tokList, gateList, cnt, out, 0);
    } else {
        // sequential per expert: Hbuf reused, combine needs no atomics (token unique per expert)
        for (int e = 0; e < kE; ++e) {
            moe_ffn1<<<dim3(kH / 128, kCap / 128, 1), 256, 0, stream>>>(
                x, W1, b1, tokList, cnt, Hbuf, 0, e);
            moe_ffn2<0><<<dim3(kD / 128, kCap / 64, 1), 256, 0, stream>>>(
                Hbuf, 0, W2, b2, tokList, gateList, cnt, out, e);
        }
    }
}

// Round 2
// 1541.190 us; speedup vs baseline: 5.7930x; 5.7930x over previous
//
#include <hip/hip_runtime.h>
#include <hip/hip_bf16.h>

namespace {
constexpr int kB = 4, kT = 4096, kD = 1024, kE = 8, kH = 4096;
constexpr int kN = kB * kT;   // 16384 tokens
constexpr int kCap = 4096;    // N*TOP_K/E * CAPACITY_FACTOR
}

typedef __attribute__((ext_vector_type(8))) short short8;
typedef __attribute__((ext_vector_type(4))) float f32x4;

static __device__ __forceinline__ unsigned short f2bf(float f) {
    __hip_bfloat16 h = __float2bfloat16(f);   // RNE
    unsigned short s;
    __builtin_memcpy(&s, &h, 2);
    return s;
}

// ---------------- zero output ----------------
__global__ __launch_bounds__(256) void moe_zero_out(float4* __restrict__ p, int n4)
{
    int i = blockIdx.x * 256 + threadIdx.x;
    if (i < n4) p[i] = make_float4(0.f, 0.f, 0.f, 0.f);
}

// ---------------- x fp32 -> bf16 ----------------
__global__ __launch_bounds__(256) void moe_cvt_x(const float4* __restrict__ in,
                                                 short8* __restrict__ outp, int n8)
{
    int i = blockIdx.x * 256 + threadIdx.x;
    if (i >= n8) return;
    const float4 a = in[2 * i], b = in[2 * i + 1];
    short8 v;
    v[0] = (short)f2bf(a.x); v[1] = (short)f2bf(a.y);
    v[2] = (short)f2bf(a.z); v[3] = (short)f2bf(a.w);
    v[4] = (short)f2bf(b.x); v[5] = (short)f2bf(b.y);
    v[6] = (short)f2bf(b.z); v[7] = (short)f2bf(b.w);
    outp[i] = v;
}

// ---------------- router: one wave per token ----------------
__global__ __launch_bounds__(256) void moe_router(
    const float* __restrict__ x, const float* __restrict__ noise_raw,
    const float* __restrict__ Wr, const float* __restrict__ br,
    const float* __restrict__ Wn, const float* __restrict__ bn,
    int2* __restrict__ topIdx, float2* __restrict__ topProb)
{
    const int wave = threadIdx.x >> 6;
    const int lane = threadIdx.x & 63;
    const int n = blockIdx.x * 4 + wave;
    const float* xr = x + (size_t)n * kD;

    float accr[kE], accn[kE];
    #pragma unroll
    for (int e = 0; e < kE; ++e) { accr[e] = 0.f; accn[e] = 0.f; }

    #pragma unroll
    for (int c = 0; c < 4; ++c) {
        const int d0 = c * 256 + lane * 4;
        const float4 xv = *(const float4*)(xr + d0);
        const float xs[4] = {xv.x, xv.y, xv.z, xv.w};
        #pragma unroll
        for (int j = 0; j < 4; ++j) {
            const float4* wr4 = (const float4*)(Wr + (size_t)(d0 + j) * kE);
            const float4* wn4 = (const float4*)(Wn + (size_t)(d0 + j) * kE);
            const float4 r0 = wr4[0], r1 = wr4[1];
            const float4 m0 = wn4[0], m1 = wn4[1];
            const float xj = xs[j];
            accr[0] += xj * r0.x; accr[1] += xj * r0.y; accr[2] += xj * r0.z; accr[3] += xj * r0.w;
            accr[4] += xj * r1.x; accr[5] += xj * r1.y; accr[6] += xj * r1.z; accr[7] += xj * r1.w;
            accn[0] += xj * m0.x; accn[1] += xj * m0.y; accn[2] += xj * m0.z; accn[3] += xj * m0.w;
            accn[4] += xj * m1.x; accn[5] += xj * m1.y; accn[6] += xj * m1.z; accn[7] += xj * m1.w;
        }
    }
    #pragma unroll
    for (int e = 0; e < kE; ++e) {
        #pragma unroll
        for (int off = 32; off >= 1; off >>= 1) {
            accr[e] += __shfl_xor(accr[e], off, 64);
            accn[e] += __shfl_xor(accn[e], off, 64);
        }
    }
    if (lane == 0) {
        float noisy[kE];
        #pragma unroll
        for (int e = 0; e < kE; ++e) {
            const float lg = accr[e] + br[e];
            const float nl = accn[e] + bn[e];
            const float sp = fmaxf(nl, 0.f) + log1pf(expf(-fabsf(nl)));
            noisy[e] = lg + noise_raw[(size_t)n * kE + e] * sp;
        }
        int i0 = 0;
        #pragma unroll
        for (int e = 1; e < kE; ++e) if (noisy[e] > noisy[i0]) i0 = e;
        int i1 = (i0 == 0) ? 1 : 0;
        #pragma unroll
        for (int e = 0; e < kE; ++e) if (e != i0 && noisy[e] > noisy[i1]) i1 = e;
        const float ex = expf(noisy[i1] - noisy[i0]);
        topIdx[n] = make_int2(i0, i1);
        topProb[n] = make_float2(1.f / (1.f + ex), ex / (1.f + ex));
    }
}

// ---------------- dispatch: stable compaction in flat token order ----------------
__global__ void moe_dispatch(
    const int2* __restrict__ topIdx, const float2* __restrict__ topProb,
    int* __restrict__ tokList, float* __restrict__ gateList, int* __restrict__ cnt)
{
    const int e = blockIdx.x;
    const int lane = threadIdx.x;   // block = 64
    const unsigned long long below = (lane == 0) ? 0ull : ((~0ull) >> (64 - lane));
    int base = 0;
    for (int it = 0; it < kN / 64; ++it) {
        const int n = it * 64 + lane;
        const int2 ti = topIdx[n];
        const float2 tp = topProb[n];
        const bool sel = (ti.x == e) || (ti.y == e);
        const float g = (ti.x == e) ? tp.x : tp.y;
        const unsigned long long m = __ballot(sel);
        if (sel) {
            const int slot = base + __popcll(m & below);
            if (slot < kCap) { tokList[e * kCap + slot] = n; gateList[e * kCap + slot] = g; }
        }
        base += __popcll(m);
    }
    if (lane == 0) cnt[e] = base < kCap ? base : kCap;
}

// ================= FFN pass 1: H = relu(Xg @ W1[e] + b1[e])  (bf16 MFMA) =================
// 128x128 tile, BK=32, 256 threads (4 waves, 2x2), 4x4 16x16x32 frags per wave.
// LDS: As[m][k], Bs[n][k], rows padded to 40 ushorts (80 B) -> conflict-free b128.
template<int AXB>
__global__ __launch_bounds__(256) void moe_ffn1_mfma(
    const float* __restrict__ x, const unsigned short* __restrict__ xb,
    const float* __restrict__ W1, const float* __restrict__ b1,
    const int* __restrict__ tokList, const int* __restrict__ cnt,
    unsigned short* __restrict__ Hbuf, int e_base)
{
    const int e = e_base + blockIdx.z;
    const int count = cnt[e];
    const int m0 = blockIdx.y * 128;
    if (m0 >= count) return;
    const int n0 = blockIdx.x * 128;

    const float* __restrict__ W = W1 + (size_t)e * kD * kH;
    const int* __restrict__ tok = tokList + e * kCap;
    unsigned short* __restrict__ H = Hbuf + (size_t)blockIdx.z * kCap * kH;

    __shared__ unsigned short As[128 * 40];
    __shared__ unsigned short Bs[128 * 40];

    const int tid = (int)threadIdx.x;
    const int srow = tid & 127;        // staging row (A) / col (B)
    const int half = tid >> 7;         // k-half: 0 or 1 (16 elems each)

    int ar = m0 + srow; if (ar >= count) ar = count - 1;
    const int t0 = tok[ar];
    const float* ax = x + (size_t)t0 * kD + half * 16;
    const unsigned short* axb = xb + (size_t)t0 * kD + half * 16;
    const float* bw = W + (size_t)(half * 16) * kH + (n0 + srow);

    const int lane = tid & 63, w = tid >> 6;
    const int wrow = (w >> 1) * 64, wcol = (w & 1) * 64;
    const int l15 = lane & 15, g = lane >> 4;

    f32x4 acc[4][4] = {};

    for (int k0 = 0; k0 < kD; k0 += 32) {
        short8 ta0, ta1, tb0, tb1;
        if (AXB) {
            ta0 = *(const short8*)(axb + k0);
            ta1 = *(const short8*)(axb + k0 + 8);
        } else {
            const float4 a0 = *(const float4*)(ax + k0);
            const float4 a1 = *(const float4*)(ax + k0 + 4);
            const float4 a2 = *(const float4*)(ax + k0 + 8);
            const float4 a3 = *(const float4*)(ax + k0 + 12);
            ta0[0] = (short)f2bf(a0.x); ta0[1] = (short)f2bf(a0.y);
            ta0[2] = (short)f2bf(a0.z); ta0[3] = (short)f2bf(a0.w);
            ta0[4] = (short)f2bf(a1.x); ta0[5] = (short)f2bf(a1.y);
            ta0[6] = (short)f2bf(a1.z); ta0[7] = (short)f2bf(a1.w);
            ta1[0] = (short)f2bf(a2.x); ta1[1] = (short)f2bf(a2.y);
            ta1[2] = (short)f2bf(a2.z); ta1[3] = (short)f2bf(a2.w);
            ta1[4] = (short)f2bf(a3.x); ta1[5] = (short)f2bf(a3.y);
            ta1[6] = (short)f2bf(a3.z); ta1[7] = (short)f2bf(a3.w);
        }
        #pragma unroll
        for (int i = 0; i < 8; ++i) tb0[i] = (short)f2bf(bw[(size_t)(k0 + i) * kH]);
        #pragma unroll
        for (int i = 0; i < 8; ++i) tb1[i] = (short)f2bf(bw[(size_t)(k0 + 8 + i) * kH]);

        __syncthreads();   // previous tile fully consumed
        *(short8*)&As[srow * 40 + half * 16] = ta0;
        *(short8*)&As[srow * 40 + half * 16 + 8] = ta1;
        *(short8*)&Bs[srow * 40 + half * 16] = tb0;
        *(short8*)&Bs[srow * 40 + half * 16 + 8] = tb1;
        __syncthreads();   // tile visible

        short8 af[4], bfr[4];
        #pragma unroll
        for (int mm = 0; mm < 4; ++mm)
            af[mm] = *(const short8*)&As[(wrow + mm * 16 + l15) * 40 + g * 8];
        #pragma unroll
        for (int nn = 0; nn < 4; ++nn)
            bfr[nn] = *(const short8*)&Bs[(wcol + nn * 16 + l15) * 40 + g * 8];
        #pragma unroll
        for (int mm = 0; mm < 4; ++mm)
            #pragma unroll
            for (int nn = 0; nn < 4; ++nn)
                acc[mm][nn] = __builtin_amdgcn_mfma_f32_16x16x32_bf16(
                    af[mm], bfr[nn], acc[mm][nn], 0, 0, 0);
    }

    const float* be = b1 + (size_t)e * kH + n0;
    #pragma unroll
    for (int mm = 0; mm < 4; ++mm) {
        #pragma unroll
        for (int i = 0; i < 4; ++i) {
            const int r = m0 + wrow + mm * 16 + g * 4 + i;
            if (r >= count) continue;
            unsigned short* hrow = H + (size_t)r * kH + n0;
            #pragma unroll
            for (int nn = 0; nn < 4; ++nn) {
                const int c = wcol + nn * 16 + l15;
                hrow[c] = f2bf(fmaxf(acc[mm][nn][i] + be[c], 0.f));
            }
        }
    }
}

// ================= FFN pass 2 + combine: out[tok] += gate * (H @ W2[e] + b2[e]) =================
__global__ __launch_bounds__(256) void moe_ffn2_mfma(
    const unsigned short* __restrict__ Hbuf,
    const float* __restrict__ W2, const float* __restrict__ b2,
    const int* __restrict__ tokList, const float* __restrict__ gateList,
    const int* __restrict__ cnt, float* __restrict__ out, int e_base)
{
    const int e = e_base + blockIdx.z;
    const int count = cnt[e];
    const int m0 = blockIdx.y * 128;
    if (m0 >= count) return;
    const int n0 = blockIdx.x * 128;

    const unsigned short* __restrict__ H = Hbuf + (size_t)blockIdx.z * kCap * kH;
    const float* __restrict__ W = W2 + (size_t)e * kH * kD;
    const int* __restrict__ tok = tokList + e * kCap;
    const float* __restrict__ gate = gateList + e * kCap;

    __shared__ unsigned short As[128 * 40];
    __shared__ unsigned short Bs[128 * 40];

    const int tid = (int)threadIdx.x;
    const int srow = tid & 127;
    const int half = tid >> 7;

    const unsigned short* ah = H + (size_t)(m0 + srow) * kH + half * 16;
    const float* bw = W + (size_t)(half * 16) * kD + (n0 + srow);

    const int lane = tid & 63, w = tid >> 6;
    const int wrow = (w >> 1) * 64, wcol = (w & 1) * 64;
    const int l15 = lane & 15, g = lane >> 4;

    f32x4 acc[4][4] = {};

    for (int k0 = 0; k0 < kH; k0 += 32) {
        const short8 ta0 = *(const short8*)(ah + k0);
        const short8 ta1 = *(const short8*)(ah + k0 + 8);
        short8 tb0, tb1;
        #pragma unroll
        for (int i = 0; i < 8; ++i) tb0[i] = (short)f2bf(bw[(size_t)(k0 + i) * kD]);
        #pragma unroll
        for (int i = 0; i < 8; ++i) tb1[i] = (short)f2bf(bw[(size_t)(k0 + 8 + i) * kD]);

        __syncthreads();
        *(short8*)&As[srow * 40 + half * 16] = ta0;
        *(short8*)&As[srow * 40 + half * 16 + 8] = ta1;
        *(short8*)&Bs[srow * 40 + half * 16] = tb0;
        *(short8*)&Bs[srow * 40 + half * 16 + 8] = tb1;
        __syncthreads();

        short8 af[4], bfr[4];
        #pragma unroll
        for (int mm = 0; mm < 4; ++mm)
            af[mm] = *(const short8*)&As[(wrow + mm * 16 + l15) * 40 + g * 8];
        #pragma unroll
        for (int nn = 0; nn < 4; ++nn)
            bfr[nn] = *(const short8*)&Bs[(wcol + nn * 16 + l15) * 40 + g * 8];
        #pragma unroll
        for (int mm = 0; mm < 4; ++mm)
            #pragma unroll
            for (int nn = 0; nn < 4; ++nn)
                acc[mm][nn] = __builtin_amdgcn_mfma_f32_16x16x32_bf16(
                    af[mm], bfr[nn], acc[mm][nn], 0, 0, 0);
    }

    const float* be = b2 + (size_t)e * kD + n0;
    #pragma unroll
    for (int mm = 0; mm < 4; ++mm) {
        #pragma unroll
        for (int i = 0; i < 4; ++i) {
            const int r = m0 + wrow + mm * 16 + g * 4 + i;
            if (r >= count) continue;
            const int tokn = tok[r];
            const float gr = gate[r];
            float* orow = out + (size_t)tokn * kD + n0;
            #pragma unroll
            for (int nn = 0; nn < 4; ++nn) {
                const int c = wcol + nn * 16 + l15;
                atomicAdd(orow + c, (acc[mm][nn][i] + be[c]) * gr);
            }
        }
    }
}

// ---------------- launch ----------------
extern "C" void kernel_launch(void* const* d_in, const int* in_sizes, int n_in,
                              void* d_out, int out_size, void* d_ws, size_t ws_size,
                              hipStream_t stream)
{
    const float* x         = (const float*)d_in[0];
    const float* noise_raw = (const float*)d_in[1];
    const float* Wr        = (const float*)d_in[2];
    const float* br        = (const float*)d_in[3];
    const float* Wn        = (const float*)d_in[4];
    const float* bn        = (const float*)d_in[5];
    const float* W1        = (const float*)d_in[6];
    const float* b1        = (const float*)d_in[7];
    const float* W2        = (const float*)d_in[8];
    const float* b2        = (const float*)d_in[9];
    float* out = (float*)d_out;

    char* ws = (char*)d_ws;
    size_t off = 0;
    auto alloc = [&](size_t bytes) -> void* {
        void* p = ws + off;
        off = (off + bytes + 255) & ~(size_t)255;
        return p;
    };
    int2*   topIdx   = (int2*)  alloc((size_t)kN * sizeof(int2));
    float2* topProb  = (float2*)alloc((size_t)kN * sizeof(float2));
    int*    tokList  = (int*)   alloc((size_t)kE * kCap * sizeof(int));
    float*  gateList = (float*) alloc((size_t)kE * kCap * sizeof(float));
    int*    cnt      = (int*)   alloc((size_t)kE * sizeof(int));

    const size_t HB  = (size_t)kCap * kH * sizeof(unsigned short);   // 32 MB per expert
    const size_t XBB = (size_t)kN * kD * sizeof(unsigned short);     // 32 MB
    int use_xb = 0;
    unsigned short* xb = nullptr;
    if (ws_size >= off + XBB + 2 * HB) {
        xb = (unsigned short*)alloc(XBB);
        use_xb = 1;
    }
    size_t rem = (ws_size > off) ? ws_size - off : 0;
    int G = (int)(rem / HB);
    if (G > kE) G = kE;
    if (G < 1) G = 1;   // ws >= 65 MB observed in round 1, so G >= 1 always holds
    unsigned short* Hbuf = (unsigned short*)(ws + off);

    moe_zero_out<<<(kN * kD / 4 + 255) / 256, 256, 0, stream>>>((float4*)out, kN * kD / 4);
    moe_router<<<kN / 4, 256, 0, stream>>>(x, noise_raw, Wr, br, Wn, bn, topIdx, topProb);
    moe_dispatch<<<kE, 64, 0, stream>>>(topIdx, topProb, tokList, gateList, cnt);
    if (use_xb)
        moe_cvt_x<<<kN * kD / 8 / 256, 256, 0, stream>>>((const float4*)x, (short8*)xb, kN * kD / 8);

    for (int e0 = 0; e0 < kE; e0 += G) {
        const int gz = (kE - e0 < G) ? (kE - e0) : G;
        if (use_xb)
            moe_ffn1_mfma<1><<<dim3(kH / 128, kCap / 128, gz), 256, 0, stream>>>(
                x, xb, W1, b1, tokList, cnt, Hbuf, e0);
        else
            moe_ffn1_mfma<0><<<dim3(kH / 128, kCap / 128, gz), 256, 0, stream>>>(
                x, xb, W1, b1, tokList, cnt, Hbuf, e0);
        moe_ffn2_mfma<<<dim3(kD / 128, kCap / 128, gz), 256, 0, stream>>>(
            Hbuf, W2, b2, tokList, gateList, cnt, out, e0);
    }
}

// Round 4
// 1260.950 us; speedup vs baseline: 7.0805x; 1.2222x over previous
//
#include <hip/hip_runtime.h>
#include <hip/hip_bf16.h>

namespace {
constexpr int kD = 1024, kE = 8, kH = 4096;
constexpr int kN = 16384;     // B*T tokens
constexpr int kCap = 4096;    // N*TOP_K/E * CAPACITY_FACTOR
}

typedef __attribute__((ext_vector_type(8))) short short8;
typedef __attribute__((ext_vector_type(4))) float f32x4;

static __device__ __forceinline__ unsigned short f2bf(float f) {
    __hip_bfloat16 h = __float2bfloat16(f);   // RNE
    unsigned short s;
    __builtin_memcpy(&s, &h, 2);
    return s;
}

// async global->LDS, 16 B per lane; LDS dest is wave-uniform base + lane*16
static __device__ __forceinline__ void gload_lds16(const unsigned short* g, unsigned short* l) {
    __builtin_amdgcn_global_load_lds(
        (const __attribute__((address_space(1))) unsigned int*)g,
        (__attribute__((address_space(3))) unsigned int*)l, 16, 0, 0);
}

// ---------------- zero output ----------------
__global__ __launch_bounds__(256) void moe_zero_out(float4* __restrict__ p, int n4)
{
    int i = blockIdx.x * 256 + threadIdx.x;
    if (i < n4) p[i] = make_float4(0.f, 0.f, 0.f, 0.f);
}

// ---------------- x fp32 -> bf16 (elementwise; x is already k-contiguous) ----------------
__global__ __launch_bounds__(256) void moe_cvt_x(const float4* __restrict__ in,
                                                 short8* __restrict__ outp, int n8)
{
    int i = blockIdx.x * 256 + threadIdx.x;
    if (i >= n8) return;
    const float4 a = in[2 * i], b = in[2 * i + 1];
    short8 v;
    v[0] = (short)f2bf(a.x); v[1] = (short)f2bf(a.y);
    v[2] = (short)f2bf(a.z); v[3] = (short)f2bf(a.w);
    v[4] = (short)f2bf(b.x); v[5] = (short)f2bf(b.y);
    v[6] = (short)f2bf(b.z); v[7] = (short)f2bf(b.w);
    outp[i] = v;
}

// ---------------- transpose + convert: in[z][R][C] fp32 -> out[z][C][R] bf16 ----------------
__global__ __launch_bounds__(256) void moe_tcvt(const float* __restrict__ in,
                                                unsigned short* __restrict__ outp,
                                                int R, int C)
{
    const float* src = in + (size_t)blockIdx.z * R * C;
    unsigned short* dst = outp + (size_t)blockIdx.z * R * C;
    const int c0 = blockIdx.x * 64, r0 = blockIdx.y * 64;
    __shared__ float t[64][68];
    const int tid = (int)threadIdx.x;
    const int tr = tid >> 2;            // 0..63
    const int tc = (tid & 3) * 16;      // 0/16/32/48
    #pragma unroll
    for (int j = 0; j < 4; ++j) {
        const float4 v = *(const float4*)(src + (size_t)(r0 + tr) * C + c0 + tc + j * 4);
        *(float4*)&t[tr][tc + j * 4] = v;
    }
    __syncthreads();
    unsigned short o[16];
    #pragma unroll
    for (int j = 0; j < 16; ++j) o[j] = f2bf(t[tc + j][tr]);
    unsigned short* dp = dst + (size_t)(c0 + tr) * R + r0 + tc;
    *(short8*)dp = *(const short8*)&o[0];
    *(short8*)(dp + 8) = *(const short8*)&o[8];
}

// ---------------- router: one wave per token ----------------
__global__ __launch_bounds__(256) void moe_router(
    const float* __restrict__ x, const float* __restrict__ noise_raw,
    const float* __restrict__ Wr, const float* __restrict__ br,
    const float* __restrict__ Wn, const float* __restrict__ bn,
    int2* __restrict__ topIdx, float2* __restrict__ topProb)
{
    const int wave = threadIdx.x >> 6;
    const int lane = threadIdx.x & 63;
    const int n = blockIdx.x * 4 + wave;
    const float* xr = x + (size_t)n * kD;

    float accr[kE], accn[kE];
    #pragma unroll
    for (int e = 0; e < kE; ++e) { accr[e] = 0.f; accn[e] = 0.f; }

    #pragma unroll
    for (int c = 0; c < 4; ++c) {
        const int d0 = c * 256 + lane * 4;
        const float4 xv = *(const float4*)(xr + d0);
        const float xs[4] = {xv.x, xv.y, xv.z, xv.w};
        #pragma unroll
        for (int j = 0; j < 4; ++j) {
            const float4* wr4 = (const float4*)(Wr + (size_t)(d0 + j) * kE);
            const float4* wn4 = (const float4*)(Wn + (size_t)(d0 + j) * kE);
            const float4 r0 = wr4[0], r1 = wr4[1];
            const float4 m0 = wn4[0], m1 = wn4[1];
            const float xj = xs[j];
            accr[0] += xj * r0.x; accr[1] += xj * r0.y; accr[2] += xj * r0.z; accr[3] += xj * r0.w;
            accr[4] += xj * r1.x; accr[5] += xj * r1.y; accr[6] += xj * r1.z; accr[7] += xj * r1.w;
            accn[0] += xj * m0.x; accn[1] += xj * m0.y; accn[2] += xj * m0.z; accn[3] += xj * m0.w;
            accn[4] += xj * m1.x; accn[5] += xj * m1.y; accn[6] += xj * m1.z; accn[7] += xj * m1.w;
        }
    }
    #pragma unroll
    for (int e = 0; e < kE; ++e) {
        #pragma unroll
        for (int off = 32; off >= 1; off >>= 1) {
            accr[e] += __shfl_xor(accr[e], off, 64);
            accn[e] += __shfl_xor(accn[e], off, 64);
        }
    }
    if (lane == 0) {
        float noisy[kE];
        #pragma unroll
        for (int e = 0; e < kE; ++e) {
            const float lg = accr[e] + br[e];
            const float nl = accn[e] + bn[e];
            const float sp = fmaxf(nl, 0.f) + log1pf(expf(-fabsf(nl)));
            noisy[e] = lg + noise_raw[(size_t)n * kE + e] * sp;
        }
        int i0 = 0;
        #pragma unroll
        for (int e = 1; e < kE; ++e) if (noisy[e] > noisy[i0]) i0 = e;
        int i1 = (i0 == 0) ? 1 : 0;
        #pragma unroll
        for (int e = 0; e < kE; ++e) if (e != i0 && noisy[e] > noisy[i1]) i1 = e;
        const float ex = expf(noisy[i1] - noisy[i0]);
        topIdx[n] = make_int2(i0, i1);
        topProb[n] = make_float2(1.f / (1.f + ex), ex / (1.f + ex));
    }
}

// ---------------- dispatch: stable compaction in flat token order ----------------
__global__ void moe_dispatch(
    const int2* __restrict__ topIdx, const float2* __restrict__ topProb,
    int* __restrict__ tokList, float* __restrict__ gateList, int* __restrict__ cnt)
{
    const int e = blockIdx.x;
    const int lane = threadIdx.x;   // block = 64
    const unsigned long long below = (lane == 0) ? 0ull : ((~0ull) >> (64 - lane));
    int base = 0;
    for (int it = 0; it < kN / 64; ++it) {
        const int n = it * 64 + lane;
        const int2 ti = topIdx[n];
        const float2 tp = topProb[n];
        const bool sel = (ti.x == e) || (ti.y == e);
        const float g = (ti.x == e) ? tp.x : tp.y;
        const unsigned long long m = __ballot(sel);
        if (sel) {
            const int slot = base + __popcll(m & below);
            if (slot < kCap) { tokList[e * kCap + slot] = n; gateList[e * kCap + slot] = g; }
        }
        base += __popcll(m);
    }
    if (lane == 0) cnt[e] = base < kCap ? base : kCap;
}

// ================= FFN pass 1: H = relu(Xg @ W1[e] + b1[e])  =================
// m97 structure: 128x128 tile, BK=32, global_load_lds width-16 staging,
// XOR-swizzled LDS (linear dest + inverse-swizzled global source), 4 waves 2x2.
__global__ __launch_bounds__(256) void moe_ffn1_g(
    const unsigned short* __restrict__ xb, const unsigned short* __restrict__ W1t,
    const float* __restrict__ b1,
    const int* __restrict__ tokList, const int* __restrict__ cnt,
    unsigned short* __restrict__ Hbuf, int e_base)
{
    const int e = e_base + blockIdx.z;
    const int count = cnt[e];
    const int m0 = blockIdx.y * 128;
    if (m0 >= count) return;
    const int n0 = blockIdx.x * 128;

    __shared__ unsigned short As[128 * 32];
    __shared__ unsigned short Bs[128 * 32];

    const int tid = (int)threadIdx.x;
    const int lane = tid & 63;
    const int w = tid >> 6;

    // ---- staging: wave w owns 1024-B chunks {2w, 2w+1} of A and B ----
    // element (row, slot s) lives at LDS byte row*64 + (s ^ ((row>>1)&3))*16;
    // linear dest => lane's global source k-offset = (slot_p ^ sigma(row_p))*8
    const int scol = ((lane & 3) ^ ((lane >> 3) & 3)) * 8;   // ushorts
    const int c0i = 2 * w, c1i = 2 * w + 1;
    const int ra0 = 16 * c0i + (lane >> 2);
    const int ra1 = 16 * c1i + (lane >> 2);
    int am0 = m0 + ra0; if (am0 >= count) am0 = count - 1;
    int am1 = m0 + ra1; if (am1 >= count) am1 = count - 1;
    const int* tok = tokList + e * kCap;
    const unsigned short* aSrc0 = xb + (size_t)tok[am0] * kD + scol;   // gather: per-lane src OK
    const unsigned short* aSrc1 = xb + (size_t)tok[am1] * kD + scol;
    const unsigned short* We = W1t + (size_t)e * kD * kH;              // [kH][kD]
    const unsigned short* bSrc0 = We + (size_t)(n0 + ra0) * kD + scol;
    const unsigned short* bSrc1 = We + (size_t)(n0 + ra1) * kD + scol;
    unsigned short* lA0 = &As[c0i * 512];
    unsigned short* lA1 = &As[c1i * 512];
    unsigned short* lB0 = &Bs[c0i * 512];
    unsigned short* lB1 = &Bs[c1i * 512];

    // ---- fragment read offsets ----
    const int l15 = lane & 15, g = lane >> 4;
    const int wrow = (w >> 1) * 64, wcol = (w & 1) * 64;
    const int fragOff = l15 * 64 + ((g ^ ((l15 >> 1) & 3)) * 16);   // bytes
    const char* Ab = (const char*)As;
    const char* Bb = (const char*)Bs;

    f32x4 acc[4][4] = {};

    for (int k0 = 0; k0 < kD; k0 += 32) {
        __syncthreads();                 // prev tile fully consumed
        gload_lds16(aSrc0 + k0, lA0);
        gload_lds16(aSrc1 + k0, lA1);
        gload_lds16(bSrc0 + k0, lB0);
        gload_lds16(bSrc1 + k0, lB1);
        __syncthreads();                 // vmcnt(0) drain -> tile visible
        short8 af[4], bfr[4];
        #pragma unroll
        for (int mm = 0; mm < 4; ++mm)
            af[mm] = *(const short8*)(Ab + (wrow + mm * 16) * 64 + fragOff);
        #pragma unroll
        for (int nn = 0; nn < 4; ++nn)
            bfr[nn] = *(const short8*)(Bb + (wcol + nn * 16) * 64 + fragOff);
        #pragma unroll
        for (int mm = 0; mm < 4; ++mm)
            #pragma unroll
            for (int nn = 0; nn < 4; ++nn)
                acc[mm][nn] = __builtin_amdgcn_mfma_f32_16x16x32_bf16(
                    af[mm], bfr[nn], acc[mm][nn], 0, 0, 0);
    }

    const float* be = b1 + (size_t)e * kH + n0;
    unsigned short* H = Hbuf + (size_t)blockIdx.z * kCap * kH;
    #pragma unroll
    for (int mm = 0; mm < 4; ++mm) {
        #pragma unroll
        for (int i = 0; i < 4; ++i) {
            const int r = m0 + wrow + mm * 16 + g * 4 + i;
            if (r >= count) continue;
            unsigned short* hrow = H + (size_t)r * kH + n0;
            #pragma unroll
            for (int nn = 0; nn < 4; ++nn) {
                const int c = wcol + nn * 16 + l15;
                hrow[c] = f2bf(fmaxf(acc[mm][nn][i] + be[c], 0.f));
            }
        }
    }
}

// ================= FFN pass 2 + combine: out[tok] += gate*(H @ W2[e] + b2[e]) =================
__global__ __launch_bounds__(256) void moe_ffn2_g(
    const unsigned short* __restrict__ Hbuf, const unsigned short* __restrict__ W2t,
    const float* __restrict__ b2,
    const int* __restrict__ tokList, const float* __restrict__ gateList,
    const int* __restrict__ cnt, float* __restrict__ out, int e_base)
{
    const int e = e_base + blockIdx.z;
    const int count = cnt[e];
    const int m0 = blockIdx.y * 128;
    if (m0 >= count) return;
    const int n0 = blockIdx.x * 128;

    __shared__ unsigned short As[128 * 32];
    __shared__ unsigned short Bs[128 * 32];

    const int tid = (int)threadIdx.x;
    const int lane = tid & 63;
    const int w = tid >> 6;

    const int scol = ((lane & 3) ^ ((lane >> 3) & 3)) * 8;
    const int c0i = 2 * w, c1i = 2 * w + 1;
    const int ra0 = 16 * c0i + (lane >> 2);
    const int ra1 = 16 * c1i + (lane >> 2);
    const unsigned short* H = Hbuf + (size_t)blockIdx.z * kCap * kH;
    const unsigned short* aSrc0 = H + (size_t)(m0 + ra0) * kH + scol;  // rows>=count read junk; masked in epilogue
    const unsigned short* aSrc1 = H + (size_t)(m0 + ra1) * kH + scol;
    const unsigned short* We = W2t + (size_t)e * kH * kD;              // [kD][kH]
    const unsigned short* bSrc0 = We + (size_t)(n0 + ra0) * kH + scol;
    const unsigned short* bSrc1 = We + (size_t)(n0 + ra1) * kH + scol;
    unsigned short* lA0 = &As[c0i * 512];
    unsigned short* lA1 = &As[c1i * 512];
    unsigned short* lB0 = &Bs[c0i * 512];
    unsigned short* lB1 = &Bs[c1i * 512];

    const int l15 = lane & 15, g = lane >> 4;
    const int wrow = (w >> 1) * 64, wcol = (w & 1) * 64;
    const int fragOff = l15 * 64 + ((g ^ ((l15 >> 1) & 3)) * 16);
    const char* Ab = (const char*)As;
    const char* Bb = (const char*)Bs;

    f32x4 acc[4][4] = {};

    for (int k0 = 0; k0 < kH; k0 += 32) {
        __syncthreads();
        gload_lds16(aSrc0 + k0, lA0);
        gload_lds16(aSrc1 + k0, lA1);
        gload_lds16(bSrc0 + k0, lB0);
        gload_lds16(bSrc1 + k0, lB1);
        __syncthreads();
        short8 af[4], bfr[4];
        #pragma unroll
        for (int mm = 0; mm < 4; ++mm)
            af[mm] = *(const short8*)(Ab + (wrow + mm * 16) * 64 + fragOff);
        #pragma unroll
        for (int nn = 0; nn < 4; ++nn)
            bfr[nn] = *(const short8*)(Bb + (wcol + nn * 16) * 64 + fragOff);
        #pragma unroll
        for (int mm = 0; mm < 4; ++mm)
            #pragma unroll
            for (int nn = 0; nn < 4; ++nn)
                acc[mm][nn] = __builtin_amdgcn_mfma_f32_16x16x32_bf16(
                    af[mm], bfr[nn], acc[mm][nn], 0, 0, 0);
    }

    const float* be = b2 + (size_t)e * kD + n0;
    const int* tok = tokList + e * kCap;
    const float* gate = gateList + e * kCap;
    #pragma unroll
    for (int mm = 0; mm < 4; ++mm) {
        #pragma unroll
        for (int i = 0; i < 4; ++i) {
            const int r = m0 + wrow + mm * 16 + g * 4 + i;
            if (r >= count) continue;
            const int tokn = tok[r];
            const float gr = gate[r];
            float* orow = out + (size_t)tokn * kD + n0;
            #pragma unroll
            for (int nn = 0; nn < 4; ++nn) {
                const int c = wcol + nn * 16 + l15;
                atomicAdd(orow + c, (acc[mm][nn][i] + be[c]) * gr);   // <=2 addends/elem: deterministic
            }
        }
    }
}

// ---------------- launch ----------------
extern "C" void kernel_launch(void* const* d_in, const int* in_sizes, int n_in,
                              void* d_out, int out_size, void* d_ws, size_t ws_size,
                              hipStream_t stream)
{
    const float* x         = (const float*)d_in[0];
    const float* noise_raw = (const float*)d_in[1];
    const float* Wr        = (const float*)d_in[2];
    const float* br        = (const float*)d_in[3];
    const float* Wn        = (const float*)d_in[4];
    const float* bn        = (const float*)d_in[5];
    const float* W1        = (const float*)d_in[6];
    const float* b1        = (const float*)d_in[7];
    const float* W2        = (const float*)d_in[8];
    const float* b2        = (const float*)d_in[9];
    float* out = (float*)d_out;

    char* ws = (char*)d_ws;
    size_t off = 0;
    auto alloc = [&](size_t bytes) -> void* {
        void* p = ws + off;
        off = (off + bytes + 255) & ~(size_t)255;
        return p;
    };
    int2*   topIdx   = (int2*)  alloc((size_t)kN * sizeof(int2));
    float2* topProb  = (float2*)alloc((size_t)kN * sizeof(float2));
    int*    tokList  = (int*)   alloc((size_t)kE * kCap * sizeof(int));
    float*  gateList = (float*) alloc((size_t)kE * kCap * sizeof(float));
    int*    cnt      = (int*)   alloc((size_t)kE * sizeof(int));

    unsigned short* xb  = (unsigned short*)alloc((size_t)kN * kD * 2);        // 32 MB
    unsigned short* W1t = (unsigned short*)alloc((size_t)kE * kD * kH * 2);   // 64 MB
    unsigned short* W2t = (unsigned short*)alloc((size_t)kE * kH * kD * 2);   // 64 MB

    const size_t HB = (size_t)kCap * kH * 2;   // 32 MB / expert
    size_t rem = (ws_size > off) ? ws_size - off : 0;
    int G = (int)(rem / HB);
    if (G > kE) G = kE;
    if (G < 1) G = 1;   // ws >= 289 MB established in round 2 -> G >= 4 in practice
    unsigned short* Hbuf = (unsigned short*)(ws + off);

    moe_zero_out<<<(kN * kD / 4 + 255) / 256, 256, 0, stream>>>((float4*)out, kN * kD / 4);
    moe_router<<<kN / 4, 256, 0, stream>>>(x, noise_raw, Wr, br, Wn, bn, topIdx, topProb);
    moe_dispatch<<<kE, 64, 0, stream>>>(topIdx, topProb, tokList, gateList, cnt);
    moe_cvt_x<<<kN * kD / 8 / 256, 256, 0, stream>>>((const float4*)x, (short8*)xb, kN * kD / 8);
    // W1 [E][D][H] -> W1t [E][H][D]
    moe_tcvt<<<dim3(kH / 64, kD / 64, kE), 256, 0, stream>>>(W1, W1t, kD, kH);
    // W2 [E][H][D] -> W2t [E][D][H]
    moe_tcvt<<<dim3(kD / 64, kH / 64, kE), 256, 0, stream>>>(W2, W2t, kH, kD);

    for (int e0 = 0; e0 < kE; e0 += G) {
        const int gz = (kE - e0 < G) ? (kE - e0) : G;
        moe_ffn1_g<<<dim3(kH / 128, kCap / 128, gz), 256, 0, stream>>>(
            xb, W1t, b1, tokList, cnt, Hbuf, e0);
        moe_ffn2_g<<<dim3(kD / 128, kCap / 128, gz), 256, 0, stream>>>(
            Hbuf, W2t, b2, tokList, gateList, cnt, out, e0);
    }
}